// Round 4
// baseline (667.768 us; speedup 1.0000x reference)
//
#include <hip/hip_runtime.h>
#include <stdint.h>

#define N_NODES 50000
#define N_EDGES 800000
#define IN_DIM 512
#define OUT_DIM 512
#define KDIM 1024   // [agg | x]
#define NDIM 1024   // [loc | scale-pre]

typedef __bf16 bf16x8 __attribute__((ext_vector_type(8)));
typedef float f32x4 __attribute__((ext_vector_type(4)));

__device__ __forceinline__ unsigned short f2bf(float f) {
    union { float f; unsigned u; } c; c.f = f;
    unsigned u = c.u;
    u += 0x7fffu + ((u >> 16) & 1u);   // round-to-nearest-even
    return (unsigned short)(u >> 16);
}
__device__ __forceinline__ float bf2f(unsigned short h) {
    union { unsigned u; float f; } c; c.u = ((unsigned)h) << 16;
    return c.f;
}

// ---------------- Phase 1: x -> bf16 ----------------
__global__ void xconv_kernel(const float* __restrict__ x, unsigned short* __restrict__ xb) {
    int i = blockIdx.x * blockDim.x + threadIdx.x;   // unit = 4 floats
    const int n4 = N_NODES * IN_DIM / 4;
    if (i < n4) {
        float4 v = ((const float4*)x)[i];
        ushort4 o;
        o.x = f2bf(v.x); o.y = f2bf(v.y); o.z = f2bf(v.z); o.w = f2bf(v.w);
        ((ushort4*)xb)[i] = o;
    }
}

// ---------------- Phase 2: CSR build ----------------
__global__ void count_kernel(const int* __restrict__ ei, int* __restrict__ counts) {
    int i = blockIdx.x * blockDim.x + threadIdx.x;
    if (i < N_EDGES) {
        int dst = ei[N_EDGES + i];
        dst = min(max(dst, 0), N_NODES - 1);
        atomicAdd(&counts[dst], 1);
    }
}

__global__ __launch_bounds__(1024) void scan_local_kernel(
    const int* __restrict__ cnt, int* __restrict__ offs,
    int* __restrict__ bsums, int n) {
    __shared__ int warp_sums[16];
    int tid = threadIdx.x;
    int lane = tid & 63;
    int w = tid >> 6;
    int i = blockIdx.x * 1024 + tid;
    int v = (i < n) ? cnt[i] : 0;
    int s = v;
    #pragma unroll
    for (int d = 1; d < 64; d <<= 1) {
        int t = __shfl_up(s, d, 64);
        if (lane >= d) s += t;
    }
    if (lane == 63) warp_sums[w] = s;
    __syncthreads();
    if (w == 0) {
        int ws = (lane < 16) ? warp_sums[lane] : 0;
        #pragma unroll
        for (int d = 1; d < 16; d <<= 1) {
            int t = __shfl_up(ws, d, 64);
            if (lane >= d) ws += t;
        }
        if (lane < 16) warp_sums[lane] = ws;
    }
    __syncthreads();
    int base = (w > 0 ? warp_sums[w - 1] : 0);
    if (i < n) offs[i] = base + s - v;
    if (tid == 1023) bsums[blockIdx.x] = base + s;
}

__global__ void scan_bsums_kernel(int* __restrict__ bsums, int nb) {
    int lane = threadIdx.x & 63;
    int v = (lane < nb) ? bsums[lane] : 0;
    int s = v;
    #pragma unroll
    for (int d = 1; d < 64; d <<= 1) {
        int t = __shfl_up(s, d, 64);
        if (lane >= d) s += t;
    }
    if (lane < nb) bsums[lane] = s - v;
}

__global__ __launch_bounds__(1024) void scan_apply_kernel(
    int* __restrict__ offs, int* __restrict__ cursor,
    const int* __restrict__ bsums, const int* __restrict__ cnt, int n) {
    int i = blockIdx.x * 1024 + threadIdx.x;
    if (i < n) {
        int o = offs[i] + bsums[blockIdx.x];
        offs[i] = o;
        cursor[i] = o;
        if (i == n - 1) offs[n] = o + cnt[i];
    }
}

__global__ void fill_kernel(const int* __restrict__ ei, int* __restrict__ cursor,
                            int* __restrict__ bucket) {
    int i = blockIdx.x * blockDim.x + threadIdx.x;
    if (i < N_EDGES) {
        int src = ei[i];
        int dst = ei[N_EDGES + i];
        src = min(max(src, 0), N_NODES - 1);
        dst = min(max(dst, 0), N_NODES - 1);
        int pos = atomicAdd(&cursor[dst], 1);
        bucket[pos] = src;
    }
}

// ---------------- Phase 3: per-node aggregation ----------------
// 1 wave/node, 16B/lane; 8-edge unroll = 8 in-flight 1KB row gathers.
__global__ __launch_bounds__(256) void aggregate_kernel(
    const unsigned short* __restrict__ xb, const int* __restrict__ offs,
    const int* __restrict__ bucket, unsigned short* __restrict__ aggb) {
    int wid = threadIdx.x >> 6;
    int lane = threadIdx.x & 63;
    int n = blockIdx.x * 4 + wid;
    if (n >= N_NODES) return;
    int beg = offs[n], end = offs[n + 1];
    float a0[8] = {}, a1[8] = {};
    int e = beg;
    for (; e + 8 <= end; e += 8) {
        int idx[8];
        #pragma unroll
        for (int u = 0; u < 8; ++u) idx[u] = bucket[e + u];
        uint4 v[8];
        #pragma unroll
        for (int u = 0; u < 8; ++u) v[u] = *(const uint4*)(xb + (size_t)idx[u] * IN_DIM + lane * 8);
        #pragma unroll
        for (int u = 0; u < 8; ++u) {
            float* a = (u & 1) ? a1 : a0;
            a[0] += bf2f((unsigned short)(v[u].x & 0xffffu)); a[1] += bf2f((unsigned short)(v[u].x >> 16));
            a[2] += bf2f((unsigned short)(v[u].y & 0xffffu)); a[3] += bf2f((unsigned short)(v[u].y >> 16));
            a[4] += bf2f((unsigned short)(v[u].z & 0xffffu)); a[5] += bf2f((unsigned short)(v[u].z >> 16));
            a[6] += bf2f((unsigned short)(v[u].w & 0xffffu)); a[7] += bf2f((unsigned short)(v[u].w >> 16));
        }
    }
    for (; e < end; ++e) {
        int s = bucket[e];
        uint4 v = *(const uint4*)(xb + (size_t)s * IN_DIM + lane * 8);
        a0[0] += bf2f((unsigned short)(v.x & 0xffffu)); a0[1] += bf2f((unsigned short)(v.x >> 16));
        a0[2] += bf2f((unsigned short)(v.y & 0xffffu)); a0[3] += bf2f((unsigned short)(v.y >> 16));
        a0[4] += bf2f((unsigned short)(v.z & 0xffffu)); a0[5] += bf2f((unsigned short)(v.z >> 16));
        a0[6] += bf2f((unsigned short)(v.w & 0xffffu)); a0[7] += bf2f((unsigned short)(v.w >> 16));
    }
    uint4 o;
    o.x = (unsigned)f2bf(a0[0] + a1[0]) | ((unsigned)f2bf(a0[1] + a1[1]) << 16);
    o.y = (unsigned)f2bf(a0[2] + a1[2]) | ((unsigned)f2bf(a0[3] + a1[3]) << 16);
    o.z = (unsigned)f2bf(a0[4] + a1[4]) | ((unsigned)f2bf(a0[5] + a1[5]) << 16);
    o.w = (unsigned)f2bf(a0[6] + a1[6]) | ((unsigned)f2bf(a0[7] + a1[7]) << 16);
    *(uint4*)(aggb + (size_t)n * IN_DIM + lane * 8) = o;
}

// ---------------- Phase 4: fuse W -> bf16 [1024][1024] ----------------
__global__ void wconv_kernel(const float* __restrict__ Wl1, const float* __restrict__ Wr1,
                             const float* __restrict__ Wl2, const float* __restrict__ Wr2,
                             unsigned short* __restrict__ Wb) {
    int i = blockIdx.x * blockDim.x + threadIdx.x;
    if (i < NDIM * KDIM) {
        int n = i >> 10, k = i & 1023;
        const float* src;
        if (n < 512) src = (k < 512) ? Wl1 : Wr1;
        else         src = (k < 512) ? Wl2 : Wr2;
        int nn = n & 511, kk = k & 511;
        Wb[i] = f2bf(src[nn * 512 + kk]);
    }
}

// ---------------- Phase 5: GEMM, 8-phase 256^2 schedule (T3+T4+T5) ----------------
// 512 threads = 8 waves (2 wr x 4 wc), wave tile 128x64, acc[8][4].
// LDS 128 KB: A dbuf 2x32KB + B dbuf 2x32KB, halves of 16KB, rows 128B,
// XOR-swizzle chunk^(row&7) (inverse-swizzled global source, swizzled ds_read).
// Per K-tile t (BK=64), 4 phases; each: {ds_read quadrant frags | stage 1
// half-tile} -> s_barrier -> setprio(1) 16 MFMA setprio(0) -> s_barrier.
// Counted vmcnt(2) once per K-tile (at p3, before the barrier preceding the
// next tile's ds_reads); never 0 in steady state. Ledger:
//   stage slots: t.p0->A1(t+1), t.p1->B0(t+1), t.p2->B1(t+1), t.p3->A0(t+2)
//   at t.p3 outstanding = {A0..B1(t+1): 8 retired-by-wait, A0(t+2): 2 left}
#define BM 256
#define BN 256
#define BK 64
#define NTT (NDIM / BN)                       // 4
#define MTT ((N_NODES + BM - 1) / BM)         // 196
#define NWG (NTT * MTT)                       // 784 = 8 * 98
#define NKT (KDIM / BK)                       // 16

__device__ __forceinline__ void async_copy16(const void* g, void* lds) {
    __builtin_amdgcn_global_load_lds((const __attribute__((address_space(1))) void*)g,
                                     (__attribute__((address_space(3))) void*)lds, 16, 0, 0);
}
#define BAR() asm volatile("s_barrier" ::: "memory")

__device__ __forceinline__ void stage_half(
    const unsigned short* __restrict__ src, int row0, int stride, int rowmax,
    int kcol0, unsigned short* ldsb, int tid) {
    #pragma unroll
    for (int iss = 0; iss < 2; ++iss) {
        int C = iss * 512 + tid;
        int lr = C >> 3, p = C & 7;
        int gr = row0 + lr; if (gr > rowmax) gr = rowmax;
        const unsigned short* g = src + (size_t)gr * stride + kcol0 + ((p ^ (lr & 7)) << 3);
        // LDS dest: wave-uniform base; HW adds lane*16B
        async_copy16(g, ldsb + (size_t)(iss * 512 + (tid & ~63)) * 8);
    }
}

__global__ __launch_bounds__(512, 2) void gemm_kernel(
    const unsigned short* __restrict__ aggb,   // [M,512] bf16
    const unsigned short* __restrict__ xb,     // [M,512] bf16
    const unsigned short* __restrict__ Wb,     // [1024,1024] bf16
    const float* __restrict__ bl1, const float* __restrict__ bl2,
    float* __restrict__ out) {
    constexpr int M = N_NODES;
    __shared__ unsigned short lds[65536];   // 128 KB: A at 0, B at 32768 (ushort units)

    // co-XCD chunk swizzle (784 % 8 == 0): each XCD gets 98 consecutive
    // logical blocks, n-tile fastest -> A panel stays in one XCD's L2.
    int bid = blockIdx.x;
    int logical = (bid & 7) * (NWG / 8) + (bid >> 3);
    int nt = logical & (NTT - 1);
    int mt = logical >> 2;
    int n0 = nt * BN;
    int m0 = mt * BM;

    int tid = threadIdx.x;
    int lane = tid & 63;
    int w = tid >> 6;
    int wr = w >> 2;    // 0..1 -> rows wr*128
    int wc = w & 3;     // 0..3 -> cols wc*64

    int fr = lane & 15, q = lane >> 4;
    int sl0 = ((q ^ (fr & 7)) << 3);        // ushort offset of logical chunk q
    int sl1 = (((q + 4) ^ (fr & 7)) << 3);  // chunk q+4 (ksub 1)

    f32x4 acc[8][4] = {};
    bf16x8 aF[4][2], bF[4][2];

    auto STAGE_A = [&](int t, int h) {
        if (t >= NKT) return;
        int kk = t * 64;
        const unsigned short* s = (kk < 512) ? aggb : xb;
        stage_half(s, m0 + h * 128, 512, M - 1, kk & 511,
                   &lds[(size_t)(t & 1) * 16384 + h * 8192], tid);
    };
    auto STAGE_B = [&](int t, int h) {
        if (t >= NKT) return;
        stage_half(Wb, n0 + h * 128, 1024, NDIM - 1, t * 64,
                   &lds[32768 + (size_t)(t & 1) * 16384 + h * 8192], tid);
    };
    auto LOAD_A = [&](int t, int ra) {
        const unsigned short* base = &lds[(size_t)(t & 1) * 16384 + wr * 8192];
        #pragma unroll
        for (int i = 0; i < 4; ++i) {
            int lr = ra * 64 + i * 16 + fr;
            aF[i][0] = *(const bf16x8*)(base + lr * 64 + sl0);
            aF[i][1] = *(const bf16x8*)(base + lr * 64 + sl1);
        }
    };
    auto LOAD_B = [&](int t, int cb) {
        const unsigned short* base = &lds[32768 + (size_t)(t & 1) * 16384 + (wc >> 1) * 8192];
        #pragma unroll
        for (int jj = 0; jj < 2; ++jj) {
            int lr = (wc & 1) * 64 + (cb * 2 + jj) * 16 + fr;
            bF[cb * 2 + jj][0] = *(const bf16x8*)(base + lr * 64 + sl0);
            bF[cb * 2 + jj][1] = *(const bf16x8*)(base + lr * 64 + sl1);
        }
    };
    #define MFMA_Q(RA, CB)                                                          \
        __builtin_amdgcn_s_setprio(1);                                              \
        _Pragma("unroll")                                                           \
        for (int i = 0; i < 4; ++i)                                                 \
            _Pragma("unroll")                                                       \
            for (int jj = 0; jj < 2; ++jj)                                          \
                _Pragma("unroll")                                                   \
                for (int ks = 0; ks < 2; ++ks)                                      \
                    acc[(RA) * 4 + i][(CB) * 2 + jj] =                              \
                        __builtin_amdgcn_mfma_f32_16x16x32_bf16(                    \
                            aF[i][ks], bF[(CB) * 2 + jj][ks],                       \
                            acc[(RA) * 4 + i][(CB) * 2 + jj], 0, 0, 0);             \
        __builtin_amdgcn_s_setprio(0);

    // prologue: t=0 fully + A0(t=1); leave A0(1) in flight
    STAGE_A(0, 0); STAGE_A(0, 1); STAGE_B(0, 0); STAGE_B(0, 1); STAGE_A(1, 0);
    asm volatile("s_waitcnt vmcnt(2)" ::: "memory");
    BAR();

    for (int t = 0; t < NKT; ++t) {
        // p0: read A-lo + B-lo quadrant; stage A1(t+1)
        LOAD_A(t, 0); LOAD_B(t, 0);
        STAGE_A(t + 1, 1);
        BAR();
        MFMA_Q(0, 0);
        BAR();
        // p1: read B-hi; stage B0(t+1)
        LOAD_B(t, 1);
        STAGE_B(t + 1, 0);
        BAR();
        MFMA_Q(0, 1);
        BAR();
        // p2: read A-hi; stage B1(t+1)
        LOAD_A(t, 1);
        STAGE_B(t + 1, 1);
        BAR();
        MFMA_Q(1, 0);
        BAR();
        // p3: stage A0(t+2); counted wait for ALL of (t+1)'s halves
        STAGE_A(t + 2, 0);
        if (t <= NKT - 3)      { asm volatile("s_waitcnt vmcnt(2)" ::: "memory"); }
        else if (t == NKT - 2) { asm volatile("s_waitcnt vmcnt(0)" ::: "memory"); }
        BAR();
        MFMA_Q(1, 1);
        BAR();
    }

    // epilogue: C/D layout col = lane&15, row = (lane>>4)*4 + reg
    bool is_scale = (n0 >= 512);
    const float* bias = is_scale ? bl2 : bl1;
    float* obase = out + (is_scale ? (size_t)N_NODES * OUT_DIM : 0);
    int ncol0 = is_scale ? (n0 - 512) : n0;
    int rq = lane >> 4;
    #pragma unroll
    for (int j = 0; j < 4; ++j) {
        int colg = ncol0 + wc * 64 + j * 16 + fr;
        float b = bias[colg];
        #pragma unroll
        for (int ia = 0; ia < 8; ++ia) {
            #pragma unroll
            for (int r = 0; r < 4; ++r) {
                int rowg = m0 + wr * 128 + ia * 16 + rq * 4 + r;
                if (rowg < M) {
                    float v = acc[ia][j][r] + b;
                    float res;
                    if (is_scale) {
                        float sp = fmaxf(v, 0.f) + __logf(1.f + __expf(-fabsf(v)));
                        res = fminf(sp + 0.001f, 100.f);
                    } else {
                        res = fminf(fmaxf(v, -100.f), 100.f);
                    }
                    __builtin_nontemporal_store(res, &obase[(size_t)rowg * OUT_DIM + colg]);
                }
            }
        }
    }
    #undef MFMA_Q
}

extern "C" void kernel_launch(void* const* d_in, const int* in_sizes, int n_in,
                              void* d_out, int out_size, void* d_ws, size_t ws_size,
                              hipStream_t stream) {
    const float* x       = (const float*)d_in[0];
    const int* ei        = (const int*)d_in[1];   // int inputs delivered as int32
    const float* Wl1     = (const float*)d_in[2];
    const float* bl1     = (const float*)d_in[3];
    const float* Wr1     = (const float*)d_in[4];
    const float* Wl2     = (const float*)d_in[5];
    const float* bl2     = (const float*)d_in[6];
    const float* Wr2     = (const float*)d_in[7];
    float* out = (float*)d_out;

    char* ws = (char*)d_ws;
    size_t off = 0;
    auto alloc = [&](size_t bytes) -> void* {
        void* p = ws + off;
        off = (off + bytes + 255) & ~(size_t)255;
        return p;
    };
    unsigned short* xb    = (unsigned short*)alloc((size_t)N_NODES * IN_DIM * 2);  // 51.2 MB
    unsigned short* aggb  = (unsigned short*)alloc((size_t)N_NODES * IN_DIM * 2);  // 51.2 MB
    unsigned short* Wb    = (unsigned short*)alloc((size_t)NDIM * KDIM * 2);       // 2 MB
    int* counts           = (int*)alloc((size_t)(N_NODES + 1) * 4);
    int* offs             = (int*)alloc((size_t)(N_NODES + 1) * 4);
    int* cursor           = (int*)alloc((size_t)N_NODES * 4);
    int* bucket           = (int*)alloc((size_t)N_EDGES * 4);                      // 3.2 MB
    int* bsums            = (int*)alloc(64 * 4);

    hipMemsetAsync(counts, 0, (size_t)(N_NODES + 1) * 4, stream);

    const int nb = (N_NODES + 1023) / 1024;   // 49

    xconv_kernel<<<(N_NODES * IN_DIM / 4 + 255) / 256, 256, 0, stream>>>(x, xb);
    count_kernel<<<(N_EDGES + 255) / 256, 256, 0, stream>>>(ei, counts);
    scan_local_kernel<<<nb, 1024, 0, stream>>>(counts, offs, bsums, N_NODES);
    scan_bsums_kernel<<<1, 64, 0, stream>>>(bsums, nb);
    scan_apply_kernel<<<nb, 1024, 0, stream>>>(offs, cursor, bsums, counts, N_NODES);
    fill_kernel<<<(N_EDGES + 255) / 256, 256, 0, stream>>>(ei, cursor, bucket);
    aggregate_kernel<<<(N_NODES + 3) / 4, 256, 0, stream>>>(xb, offs, bucket, aggb);
    wconv_kernel<<<(NDIM * KDIM + 255) / 256, 256, 0, stream>>>(Wl1, Wr1, Wl2, Wr2, Wb);

    gemm_kernel<<<NWG, 512, 0, stream>>>(aggb, xb, Wb, bl1, bl2, out);
}

// Round 5
// 622.841 us; speedup vs baseline: 1.0721x; 1.0721x over previous
//
#include <hip/hip_runtime.h>
#include <stdint.h>

#define N_NODES 50000
#define N_EDGES 800000
#define IN_DIM 512
#define OUT_DIM 512
#define KDIM 1024   // [agg | x]
#define NDIM 1024   // [loc | scale-pre]

typedef __bf16 bf16x8 __attribute__((ext_vector_type(8)));
typedef float f32x4 __attribute__((ext_vector_type(4)));

__device__ __forceinline__ unsigned short f2bf(float f) {
    union { float f; unsigned u; } c; c.f = f;
    unsigned u = c.u;
    u += 0x7fffu + ((u >> 16) & 1u);   // round-to-nearest-even
    return (unsigned short)(u >> 16);
}
__device__ __forceinline__ float bf2f(unsigned short h) {
    union { unsigned u; float f; } c; c.u = ((unsigned)h) << 16;
    return c.f;
}

// ---------------- Phase 1 (fused): x->bf16 | edge count | W fuse ----------------
#define XCONV_BLOCKS ((N_NODES * IN_DIM / 4 + 255) / 256)     // 25000
#define COUNT_BLOCKS ((N_EDGES + 255) / 256)                  // 3125
#define WCONV_BLOCKS ((NDIM * KDIM + 255) / 256)              // 4096

__global__ __launch_bounds__(256) void prep_kernel(
    const float* __restrict__ x, unsigned short* __restrict__ xb,
    const int* __restrict__ ei, int* __restrict__ counts,
    const float* __restrict__ Wl1, const float* __restrict__ Wr1,
    const float* __restrict__ Wl2, const float* __restrict__ Wr2,
    unsigned short* __restrict__ Wb) {
    int b = blockIdx.x;
    if (b < XCONV_BLOCKS) {
        int i = b * 256 + threadIdx.x;   // unit = 4 floats
        const int n4 = N_NODES * IN_DIM / 4;
        if (i < n4) {
            float4 v = ((const float4*)x)[i];
            ushort4 o;
            o.x = f2bf(v.x); o.y = f2bf(v.y); o.z = f2bf(v.z); o.w = f2bf(v.w);
            ((ushort4*)xb)[i] = o;
        }
    } else if (b < XCONV_BLOCKS + COUNT_BLOCKS) {
        int i = (b - XCONV_BLOCKS) * 256 + threadIdx.x;
        if (i < N_EDGES) {
            int dst = ei[N_EDGES + i];
            dst = min(max(dst, 0), N_NODES - 1);   // defensive clamp
            atomicAdd(&counts[dst], 1);
        }
    } else {
        int i = (b - XCONV_BLOCKS - COUNT_BLOCKS) * 256 + threadIdx.x;
        if (i < NDIM * KDIM) {
            int n = i >> 10, k = i & 1023;
            const float* src;
            if (n < 512) src = (k < 512) ? Wl1 : Wr1;
            else         src = (k < 512) ? Wl2 : Wr2;
            int nn = n & 511, kk = k & 511;
            Wb[i] = f2bf(src[nn * 512 + kk]);
        }
    }
}

// ---------------- Phase 2: CSR scan ----------------
__global__ __launch_bounds__(1024) void scan_local_kernel(
    const int* __restrict__ cnt, int* __restrict__ offs,
    int* __restrict__ bsums, int n) {
    __shared__ int warp_sums[16];
    int tid = threadIdx.x;
    int lane = tid & 63;
    int w = tid >> 6;
    int i = blockIdx.x * 1024 + tid;
    int v = (i < n) ? cnt[i] : 0;
    int s = v;
    #pragma unroll
    for (int d = 1; d < 64; d <<= 1) {
        int t = __shfl_up(s, d, 64);
        if (lane >= d) s += t;
    }
    if (lane == 63) warp_sums[w] = s;
    __syncthreads();
    if (w == 0) {
        int ws = (lane < 16) ? warp_sums[lane] : 0;
        #pragma unroll
        for (int d = 1; d < 16; d <<= 1) {
            int t = __shfl_up(ws, d, 64);
            if (lane >= d) ws += t;
        }
        if (lane < 16) warp_sums[lane] = ws;
    }
    __syncthreads();
    int base = (w > 0 ? warp_sums[w - 1] : 0);
    if (i < n) offs[i] = base + s - v;
    if (tid == 1023) bsums[blockIdx.x] = base + s;
}

// apply: each block reduces its own bsums prefix (<=64 entries) in one wave
__global__ __launch_bounds__(1024) void scan_apply_kernel(
    int* __restrict__ offs, int* __restrict__ cursor,
    const int* __restrict__ bsums, const int* __restrict__ cnt, int n) {
    __shared__ int s_base;
    int tid = threadIdx.x;
    if (tid < 64) {
        int v = (tid < (int)blockIdx.x) ? bsums[tid] : 0;
        #pragma unroll
        for (int d = 32; d > 0; d >>= 1) v += __shfl_down(v, d, 64);
        if (tid == 0) s_base = v;
    }
    __syncthreads();
    int i = blockIdx.x * 1024 + tid;
    if (i < n) {
        int o = offs[i] + s_base;
        offs[i] = o;
        cursor[i] = o;
        if (i == n - 1) offs[n] = o + cnt[i];
    }
}

__global__ void fill_kernel(const int* __restrict__ ei, int* __restrict__ cursor,
                            int* __restrict__ bucket) {
    int i = blockIdx.x * blockDim.x + threadIdx.x;
    if (i < N_EDGES) {
        int src = ei[i];
        int dst = ei[N_EDGES + i];
        src = min(max(src, 0), N_NODES - 1);
        dst = min(max(dst, 0), N_NODES - 1);
        int pos = atomicAdd(&cursor[dst], 1);
        bucket[pos] = src;
    }
}

// ---------------- Phase 3: per-node aggregation ----------------
// 1 wave/node, 16B/lane; 8-edge unroll = 8 in-flight 1KB row gathers.
__global__ __launch_bounds__(256) void aggregate_kernel(
    const unsigned short* __restrict__ xb, const int* __restrict__ offs,
    const int* __restrict__ bucket, unsigned short* __restrict__ aggb) {
    int wid = threadIdx.x >> 6;
    int lane = threadIdx.x & 63;
    int n = blockIdx.x * 4 + wid;
    if (n >= N_NODES) return;
    int beg = offs[n], end = offs[n + 1];
    float a0[8] = {}, a1[8] = {};
    int e = beg;
    for (; e + 8 <= end; e += 8) {
        int idx[8];
        #pragma unroll
        for (int u = 0; u < 8; ++u) idx[u] = bucket[e + u];
        uint4 v[8];
        #pragma unroll
        for (int u = 0; u < 8; ++u) v[u] = *(const uint4*)(xb + (size_t)idx[u] * IN_DIM + lane * 8);
        #pragma unroll
        for (int u = 0; u < 8; ++u) {
            float* a = (u & 1) ? a1 : a0;
            a[0] += bf2f((unsigned short)(v[u].x & 0xffffu)); a[1] += bf2f((unsigned short)(v[u].x >> 16));
            a[2] += bf2f((unsigned short)(v[u].y & 0xffffu)); a[3] += bf2f((unsigned short)(v[u].y >> 16));
            a[4] += bf2f((unsigned short)(v[u].z & 0xffffu)); a[5] += bf2f((unsigned short)(v[u].z >> 16));
            a[6] += bf2f((unsigned short)(v[u].w & 0xffffu)); a[7] += bf2f((unsigned short)(v[u].w >> 16));
        }
    }
    for (; e < end; ++e) {
        int s = bucket[e];
        uint4 v = *(const uint4*)(xb + (size_t)s * IN_DIM + lane * 8);
        a0[0] += bf2f((unsigned short)(v.x & 0xffffu)); a0[1] += bf2f((unsigned short)(v.x >> 16));
        a0[2] += bf2f((unsigned short)(v.y & 0xffffu)); a0[3] += bf2f((unsigned short)(v.y >> 16));
        a0[4] += bf2f((unsigned short)(v.z & 0xffffu)); a0[5] += bf2f((unsigned short)(v.z >> 16));
        a0[6] += bf2f((unsigned short)(v.w & 0xffffu)); a0[7] += bf2f((unsigned short)(v.w >> 16));
    }
    uint4 o;
    o.x = (unsigned)f2bf(a0[0] + a1[0]) | ((unsigned)f2bf(a0[1] + a1[1]) << 16);
    o.y = (unsigned)f2bf(a0[2] + a1[2]) | ((unsigned)f2bf(a0[3] + a1[3]) << 16);
    o.z = (unsigned)f2bf(a0[4] + a1[4]) | ((unsigned)f2bf(a0[5] + a1[5]) << 16);
    o.w = (unsigned)f2bf(a0[6] + a1[6]) | ((unsigned)f2bf(a0[7] + a1[7]) << 16);
    *(uint4*)(aggb + (size_t)n * IN_DIM + lane * 8) = o;
}

// ---------------- Phase 5: GEMM, 2-phase double-buffered (T3-minimum) ----------------
// r3 geometry (BM=BN=128, BK=64, 256 thr, co-XCD swizzle, XOR-swizzled LDS) +
// LDS double-buffer: STAGE(next) -> ds_read(cur)+MFMA -> ONE __syncthreads per
// K-step. The compiler's barrier-attached vmcnt(0) drain now lands AFTER the
// compute section, so the staging latency hides under 32 MFMAs + 16 ds_reads.
// 64KB LDS -> 2 blocks/CU. Double-step loop keeps buffer indices compile-time.
#define BM 128
#define BN 128
#define BK 64
#define NT_TILES (NDIM / BN)                       // 8
#define MT_TILES ((N_NODES + BM - 1) / BM)         // 391
#define NWG (NT_TILES * MT_TILES)                  // 3128 = 8 * 391
#define NKT (KDIM / BK)                            // 16

__device__ __forceinline__ void async_copy16(const void* g, void* lds) {
    __builtin_amdgcn_global_load_lds((const __attribute__((address_space(1))) void*)g,
                                     (__attribute__((address_space(3))) void*)lds, 16, 0, 0);
}

__global__ __launch_bounds__(256, 2) void gemm_kernel(
    const unsigned short* __restrict__ aggb,   // [M,512] bf16
    const unsigned short* __restrict__ xb,     // [M,512] bf16
    const unsigned short* __restrict__ Wb,     // [1024,1024] bf16
    const float* __restrict__ bl1, const float* __restrict__ bl2,
    float* __restrict__ out) {
    constexpr int M = N_NODES;
    __shared__ unsigned short sA[2][BM * BK];   // 2 x 16 KB
    __shared__ unsigned short sB[2][BN * BK];   // 2 x 16 KB

    // co-XCD chunk swizzle: physical bid -> xcd = bid&7, slot = bid>>3;
    // logical = xcd*391 + slot keeps each m-row's 8 n-tiles on one XCD.
    int bid = blockIdx.x;
    int logical = (bid & 7) * (NWG / 8) + (bid >> 3);
    int nt = logical & (NT_TILES - 1);
    int mt = logical >> 3;
    int n0 = nt * BN;
    int m0 = mt * BM;

    int tid = threadIdx.x;
    int lane = tid & 63;
    int w = tid >> 6;
    int wm = (w >> 1) * 64, wn = (w & 1) * 64;

    f32x4 acc[4][4] = {};

    int fr = lane & 15, q = lane >> 4;
    // fragment-read swizzled chunk offsets (row&7 == fr&7: wm,wn,i*16 mult. of 8)
    int sl0 = ((q ^ (fr & 7)) << 3);        // ushort offset of logical chunk q
    int sl1 = (((q + 4) ^ (fr & 7)) << 3);  // chunk q+4 (ksub 1)

    // stage K-tile t into buffer buf; slot p of row r holds logical chunk p^(r&7)
    auto STAGE = [&](int t, int buf) {
        if (t >= NKT) return;
        int kk = t * BK;
        const unsigned short* Asrc = (kk < 512) ? aggb : xb;
        int ak = kk & 511;
        #pragma unroll
        for (int iss = 0; iss < 4; ++iss) {
            int C = iss * 256 + tid;
            int r = C >> 3, p = C & 7;
            int gr = m0 + r; if (gr >= M) gr = M - 1;
            const unsigned short* g = Asrc + (size_t)gr * 512 + ak + ((p ^ (r & 7)) << 3);
            async_copy16(g, &sA[buf][(size_t)(iss * 256 + (tid & ~63)) * 8]);
        }
        #pragma unroll
        for (int iss = 0; iss < 4; ++iss) {
            int C = iss * 256 + tid;
            int r = C >> 3, p = C & 7;
            const unsigned short* g = Wb + (size_t)(n0 + r) * KDIM + kk + ((p ^ (r & 7)) << 3);
            async_copy16(g, &sB[buf][(size_t)(iss * 256 + (tid & ~63)) * 8]);
        }
    };
    auto COMPUTE = [&](int buf) {
        #pragma unroll
        for (int ksub = 0; ksub < 2; ++ksub) {
            int sl = ksub ? sl1 : sl0;
            bf16x8 af[4], bfg[4];
            #pragma unroll
            for (int i = 0; i < 4; ++i)
                af[i] = *(const bf16x8*)(&sA[buf][0] + (wm + i * 16 + fr) * BK + sl);
            #pragma unroll
            for (int j = 0; j < 4; ++j)
                bfg[j] = *(const bf16x8*)(&sB[buf][0] + (wn + j * 16 + fr) * BK + sl);
            #pragma unroll
            for (int i = 0; i < 4; ++i)
                #pragma unroll
                for (int j = 0; j < 4; ++j)
                    acc[i][j] = __builtin_amdgcn_mfma_f32_16x16x32_bf16(af[i], bfg[j], acc[i][j], 0, 0, 0);
        }
    };

    STAGE(0, 0);
    __syncthreads();   // drains prologue loads
    for (int t = 0; t < NKT; t += 2) {
        STAGE(t + 1, 1);      // issue next-tile loads first (latency under compute)
        COMPUTE(0);           // consume buf 0 (tile t)
        __syncthreads();      // vmcnt(0)+lgkmcnt(0)+barrier: buf1 ready, buf0 free
        STAGE(t + 2, 0);
        COMPUTE(1);           // tile t+1
        __syncthreads();
    }

    // epilogue: C/D layout col = lane&15, row = (lane>>4)*4 + reg
    bool is_scale = (n0 >= 512);
    const float* bias = is_scale ? bl2 : bl1;
    float* obase = out + (is_scale ? (size_t)N_NODES * OUT_DIM : 0);
    int ncol0 = is_scale ? (n0 - 512) : n0;
    int rq = lane >> 4;
    #pragma unroll
    for (int i = 0; i < 4; ++i) {
        #pragma unroll
        for (int j = 0; j < 4; ++j) {
            int colg = ncol0 + wn + j * 16 + fr;
            float b = bias[colg];
            #pragma unroll
            for (int r = 0; r < 4; ++r) {
                int rowg = m0 + wm + i * 16 + rq * 4 + r;
                if (rowg < M) {
                    float v = acc[i][j][r] + b;
                    float res;
                    if (is_scale) {
                        float sp = fmaxf(v, 0.f) + __logf(1.f + __expf(-fabsf(v)));
                        res = fminf(sp + 0.001f, 100.f);
                    } else {
                        res = fminf(fmaxf(v, -100.f), 100.f);
                    }
                    __builtin_nontemporal_store(res, &obase[(size_t)rowg * OUT_DIM + colg]);
                }
            }
        }
    }
}

extern "C" void kernel_launch(void* const* d_in, const int* in_sizes, int n_in,
                              void* d_out, int out_size, void* d_ws, size_t ws_size,
                              hipStream_t stream) {
    const float* x       = (const float*)d_in[0];
    const int* ei        = (const int*)d_in[1];   // int inputs delivered as int32
    const float* Wl1     = (const float*)d_in[2];
    const float* bl1     = (const float*)d_in[3];
    const float* Wr1     = (const float*)d_in[4];
    const float* Wl2     = (const float*)d_in[5];
    const float* bl2     = (const float*)d_in[6];
    const float* Wr2     = (const float*)d_in[7];
    float* out = (float*)d_out;

    char* ws = (char*)d_ws;
    size_t off = 0;
    auto alloc = [&](size_t bytes) -> void* {
        void* p = ws + off;
        off = (off + bytes + 255) & ~(size_t)255;
        return p;
    };
    unsigned short* xb    = (unsigned short*)alloc((size_t)N_NODES * IN_DIM * 2);  // 51.2 MB
    unsigned short* aggb  = (unsigned short*)alloc((size_t)N_NODES * IN_DIM * 2);  // 51.2 MB
    unsigned short* Wb    = (unsigned short*)alloc((size_t)NDIM * KDIM * 2);       // 2 MB
    int* counts           = (int*)alloc((size_t)(N_NODES + 1) * 4);
    int* offs             = (int*)alloc((size_t)(N_NODES + 1) * 4);
    int* cursor           = (int*)alloc((size_t)N_NODES * 4);
    int* bucket           = (int*)alloc((size_t)N_EDGES * 4);                      // 3.2 MB
    int* bsums            = (int*)alloc(64 * 4);

    hipMemsetAsync(counts, 0, (size_t)(N_NODES + 1) * 4, stream);

    const int nb = (N_NODES + 1023) / 1024;   // 49

    prep_kernel<<<XCONV_BLOCKS + COUNT_BLOCKS + WCONV_BLOCKS, 256, 0, stream>>>(
        x, xb, ei, counts, Wl1, Wr1, Wl2, Wr2, Wb);
    scan_local_kernel<<<nb, 1024, 0, stream>>>(counts, offs, bsums, N_NODES);
    scan_apply_kernel<<<nb, 1024, 0, stream>>>(offs, cursor, bsums, counts, N_NODES);
    fill_kernel<<<(N_EDGES + 255) / 256, 256, 0, stream>>>(ei, cursor, bucket);
    aggregate_kernel<<<(N_NODES + 3) / 4, 256, 0, stream>>>(xb, offs, bucket, aggb);

    gemm_kernel<<<NWG, 256, 0, stream>>>(aggb, xb, Wb, bl1, bl2, out);
}

// Round 6
// 578.399 us; speedup vs baseline: 1.1545x; 1.0768x over previous
//
#include <hip/hip_runtime.h>
#include <stdint.h>

#define N_NODES 50000
#define N_EDGES 800000
#define IN_DIM 512
#define OUT_DIM 512
#define KDIM 1024   // [agg | x]
#define NDIM 1024   // [loc | scale-pre]

typedef __bf16 bf16x8 __attribute__((ext_vector_type(8)));
typedef float f32x4 __attribute__((ext_vector_type(4)));

__device__ __forceinline__ unsigned short f2bf(float f) {
    union { float f; unsigned u; } c; c.f = f;
    unsigned u = c.u;
    u += 0x7fffu + ((u >> 16) & 1u);   // round-to-nearest-even
    return (unsigned short)(u >> 16);
}
__device__ __forceinline__ float bf2f(unsigned short h) {
    union { unsigned u; float f; } c; c.u = ((unsigned)h) << 16;
    return c.f;
}

// ---------------- Phase 1 (fused): x->bf16 | edge count | W fuse ----------------
#define XCONV_BLOCKS ((N_NODES * IN_DIM / 4 + 255) / 256)     // 25000
#define COUNT_BLOCKS ((N_EDGES + 255) / 256)                  // 3125
#define WCONV_BLOCKS ((NDIM * KDIM + 255) / 256)              // 4096

__global__ __launch_bounds__(256) void prep_kernel(
    const float* __restrict__ x, unsigned short* __restrict__ xb,
    const int* __restrict__ ei, int* __restrict__ counts,
    const float* __restrict__ Wl1, const float* __restrict__ Wr1,
    const float* __restrict__ Wl2, const float* __restrict__ Wr2,
    unsigned short* __restrict__ Wb) {
    int b = blockIdx.x;
    if (b < XCONV_BLOCKS) {
        int i = b * 256 + threadIdx.x;   // unit = 4 floats
        const int n4 = N_NODES * IN_DIM / 4;
        if (i < n4) {
            float4 v = ((const float4*)x)[i];
            ushort4 o;
            o.x = f2bf(v.x); o.y = f2bf(v.y); o.z = f2bf(v.z); o.w = f2bf(v.w);
            ((ushort4*)xb)[i] = o;
        }
    } else if (b < XCONV_BLOCKS + COUNT_BLOCKS) {
        int i = (b - XCONV_BLOCKS) * 256 + threadIdx.x;
        if (i < N_EDGES) {
            int dst = ei[N_EDGES + i];
            dst = min(max(dst, 0), N_NODES - 1);   // defensive clamp
            atomicAdd(&counts[dst], 1);
        }
    } else {
        int i = (b - XCONV_BLOCKS - COUNT_BLOCKS) * 256 + threadIdx.x;
        if (i < NDIM * KDIM) {
            int n = i >> 10, k = i & 1023;
            const float* src;
            if (n < 512) src = (k < 512) ? Wl1 : Wr1;
            else         src = (k < 512) ? Wl2 : Wr2;
            int nn = n & 511, kk = k & 511;
            Wb[i] = f2bf(src[nn * 512 + kk]);
        }
    }
}

// ---------------- Phase 2: CSR scan ----------------
__global__ __launch_bounds__(1024) void scan_local_kernel(
    const int* __restrict__ cnt, int* __restrict__ offs,
    int* __restrict__ bsums, int n) {
    __shared__ int warp_sums[16];
    int tid = threadIdx.x;
    int lane = tid & 63;
    int w = tid >> 6;
    int i = blockIdx.x * 1024 + tid;
    int v = (i < n) ? cnt[i] : 0;
    int s = v;
    #pragma unroll
    for (int d = 1; d < 64; d <<= 1) {
        int t = __shfl_up(s, d, 64);
        if (lane >= d) s += t;
    }
    if (lane == 63) warp_sums[w] = s;
    __syncthreads();
    if (w == 0) {
        int ws = (lane < 16) ? warp_sums[lane] : 0;
        #pragma unroll
        for (int d = 1; d < 16; d <<= 1) {
            int t = __shfl_up(ws, d, 64);
            if (lane >= d) ws += t;
        }
        if (lane < 16) warp_sums[lane] = ws;
    }
    __syncthreads();
    int base = (w > 0 ? warp_sums[w - 1] : 0);
    if (i < n) offs[i] = base + s - v;
    if (tid == 1023) bsums[blockIdx.x] = base + s;
}

// apply: each block reduces its own bsums prefix (<=64 entries) in one wave
__global__ __launch_bounds__(1024) void scan_apply_kernel(
    int* __restrict__ offs, int* __restrict__ cursor,
    const int* __restrict__ bsums, const int* __restrict__ cnt, int n) {
    __shared__ int s_base;
    int tid = threadIdx.x;
    if (tid < 64) {
        int v = (tid < (int)blockIdx.x) ? bsums[tid] : 0;
        #pragma unroll
        for (int d = 32; d > 0; d >>= 1) v += __shfl_down(v, d, 64);
        if (tid == 0) s_base = v;
    }
    __syncthreads();
    int i = blockIdx.x * 1024 + tid;
    if (i < n) {
        int o = offs[i] + s_base;
        offs[i] = o;
        cursor[i] = o;
        if (i == n - 1) offs[n] = o + cnt[i];
    }
}

__global__ void fill_kernel(const int* __restrict__ ei, int* __restrict__ cursor,
                            int* __restrict__ bucket) {
    int i = blockIdx.x * blockDim.x + threadIdx.x;
    if (i < N_EDGES) {
        int src = ei[i];
        int dst = ei[N_EDGES + i];
        src = min(max(src, 0), N_NODES - 1);
        dst = min(max(dst, 0), N_NODES - 1);
        int pos = atomicAdd(&cursor[dst], 1);
        bucket[pos] = src;
    }
}

// ---------------- Phase 3: per-node aggregation ----------------
// 1 wave/node, 16B/lane; 8-edge unroll = 8 in-flight 1KB row gathers.
__global__ __launch_bounds__(256) void aggregate_kernel(
    const unsigned short* __restrict__ xb, const int* __restrict__ offs,
    const int* __restrict__ bucket, unsigned short* __restrict__ aggb) {
    int wid = threadIdx.x >> 6;
    int lane = threadIdx.x & 63;
    int n = blockIdx.x * 4 + wid;
    if (n >= N_NODES) return;
    int beg = offs[n], end = offs[n + 1];
    float a0[8] = {}, a1[8] = {};
    int e = beg;
    for (; e + 8 <= end; e += 8) {
        int idx[8];
        #pragma unroll
        for (int u = 0; u < 8; ++u) idx[u] = bucket[e + u];
        uint4 v[8];
        #pragma unroll
        for (int u = 0; u < 8; ++u) v[u] = *(const uint4*)(xb + (size_t)idx[u] * IN_DIM + lane * 8);
        #pragma unroll
        for (int u = 0; u < 8; ++u) {
            float* a = (u & 1) ? a1 : a0;
            a[0] += bf2f((unsigned short)(v[u].x & 0xffffu)); a[1] += bf2f((unsigned short)(v[u].x >> 16));
            a[2] += bf2f((unsigned short)(v[u].y & 0xffffu)); a[3] += bf2f((unsigned short)(v[u].y >> 16));
            a[4] += bf2f((unsigned short)(v[u].z & 0xffffu)); a[5] += bf2f((unsigned short)(v[u].z >> 16));
            a[6] += bf2f((unsigned short)(v[u].w & 0xffffu)); a[7] += bf2f((unsigned short)(v[u].w >> 16));
        }
    }
    for (; e < end; ++e) {
        int s = bucket[e];
        uint4 v = *(const uint4*)(xb + (size_t)s * IN_DIM + lane * 8);
        a0[0] += bf2f((unsigned short)(v.x & 0xffffu)); a0[1] += bf2f((unsigned short)(v.x >> 16));
        a0[2] += bf2f((unsigned short)(v.y & 0xffffu)); a0[3] += bf2f((unsigned short)(v.y >> 16));
        a0[4] += bf2f((unsigned short)(v.z & 0xffffu)); a0[5] += bf2f((unsigned short)(v.z >> 16));
        a0[6] += bf2f((unsigned short)(v.w & 0xffffu)); a0[7] += bf2f((unsigned short)(v.w >> 16));
    }
    uint4 o;
    o.x = (unsigned)f2bf(a0[0] + a1[0]) | ((unsigned)f2bf(a0[1] + a1[1]) << 16);
    o.y = (unsigned)f2bf(a0[2] + a1[2]) | ((unsigned)f2bf(a0[3] + a1[3]) << 16);
    o.z = (unsigned)f2bf(a0[4] + a1[4]) | ((unsigned)f2bf(a0[5] + a1[5]) << 16);
    o.w = (unsigned)f2bf(a0[6] + a1[6]) | ((unsigned)f2bf(a0[7] + a1[7]) << 16);
    *(uint4*)(aggb + (size_t)n * IN_DIM + lane * 8) = o;
}

// ---------------- Phase 5: GEMM (r3-exact): single-buffer, 2-barrier, co-XCD ----------------
// BM=BN=128, BK=64, 256 thr, 32KB LDS -> 3 blocks/CU (implicit wave-level overlap
// does the pipelining; both explicit-pipeline variants lost to occupancy).
// XOR-swizzle chunk^(row&7): inverse-swizzled global source + swizzled ds_read.
#define BM 128
#define BN 128
#define BK 64
#define NT_TILES (NDIM / BN)                       // 8
#define MT_TILES ((N_NODES + BM - 1) / BM)         // 391
#define NWG (NT_TILES * MT_TILES)                  // 3128 = 8 * 391

__device__ __forceinline__ void async_copy16(const void* g, void* lds) {
    __builtin_amdgcn_global_load_lds((const __attribute__((address_space(1))) void*)g,
                                     (__attribute__((address_space(3))) void*)lds, 16, 0, 0);
}

__global__ __launch_bounds__(256, 2) void gemm_kernel(
    const unsigned short* __restrict__ aggb,   // [M,512] bf16
    const unsigned short* __restrict__ xb,     // [M,512] bf16
    const unsigned short* __restrict__ Wb,     // [1024,1024] bf16
    const float* __restrict__ bl1, const float* __restrict__ bl2,
    float* __restrict__ out) {
    constexpr int M = N_NODES;
    __shared__ unsigned short sA[BM * BK];   // 16 KB
    __shared__ unsigned short sB[BN * BK];   // 16 KB

    // co-XCD chunk swizzle: physical bid -> xcd = bid&7, slot = bid>>3;
    // logical = xcd*391 + slot keeps each m-row's 8 n-tiles on one XCD.
    int bid = blockIdx.x;
    int logical = (bid & 7) * (NWG / 8) + (bid >> 3);
    int nt = logical & (NT_TILES - 1);
    int mt = logical >> 3;
    int n0 = nt * BN;
    int m0 = mt * BM;

    int tid = threadIdx.x;
    int lane = tid & 63;
    int w = tid >> 6;
    int wm = (w >> 1) * 64, wn = (w & 1) * 64;

    f32x4 acc[4][4] = {};

    int fr = lane & 15, q = lane >> 4;
    // fragment-read swizzled chunk offsets (row&7 == fr&7 since wm,wn,i*16 are mult. of 8)
    int sl0 = ((q ^ (fr & 7)) << 3);        // bf16 offset of logical chunk q   (ksub 0)
    int sl1 = (((q + 4) ^ (fr & 7)) << 3);  // bf16 offset of logical chunk q+4 (ksub 1)

    for (int k0 = 0; k0 < KDIM; k0 += BK) {
        const unsigned short* Asrc;
        int ak;
        if (k0 < 512) { Asrc = aggb; ak = k0; } else { Asrc = xb; ak = k0 - 512; }
        // staging: linear chunk C = iss*256 + tid -> LDS 16B slot C;
        // slot p of row r must hold logical chunk (p ^ (r&7)) -> fetch that from global.
        #pragma unroll
        for (int iss = 0; iss < 4; ++iss) {
            int C = iss * 256 + tid;
            int r = C >> 3, p = C & 7;
            int gr = m0 + r; if (gr >= M) gr = M - 1;
            const unsigned short* g = Asrc + (size_t)gr * 512 + ak + ((p ^ (r & 7)) << 3);
            async_copy16(g, sA + (size_t)(iss * 256 + w * 64) * 8);
        }
        #pragma unroll
        for (int iss = 0; iss < 4; ++iss) {
            int C = iss * 256 + tid;
            int r = C >> 3, p = C & 7;
            const unsigned short* g = Wb + (size_t)(n0 + r) * KDIM + k0 + ((p ^ (r & 7)) << 3);
            async_copy16(g, sB + (size_t)(iss * 256 + w * 64) * 8);
        }
        __syncthreads();

        #pragma unroll
        for (int ksub = 0; ksub < 2; ++ksub) {
            int sl = ksub ? sl1 : sl0;
            bf16x8 af[4], bfg[4];
            #pragma unroll
            for (int i = 0; i < 4; ++i)
                af[i] = *(const bf16x8*)(sA + (wm + i * 16 + fr) * BK + sl);
            #pragma unroll
            for (int j = 0; j < 4; ++j)
                bfg[j] = *(const bf16x8*)(sB + (wn + j * 16 + fr) * BK + sl);
            #pragma unroll
            for (int i = 0; i < 4; ++i)
                #pragma unroll
                for (int j = 0; j < 4; ++j)
                    acc[i][j] = __builtin_amdgcn_mfma_f32_16x16x32_bf16(af[i], bfg[j], acc[i][j], 0, 0, 0);
        }
        __syncthreads();
    }

    // epilogue: C/D layout col = lane&15, row = (lane>>4)*4 + reg
    bool is_scale = (n0 >= 512);                 // BN=128 divides 512, so uniform per block
    const float* bias = is_scale ? bl2 : bl1;
    float* obase = out + (is_scale ? (size_t)N_NODES * OUT_DIM : 0);
    int ncol0 = is_scale ? (n0 - 512) : n0;
    int rq = lane >> 4;
    #pragma unroll
    for (int i = 0; i < 4; ++i) {
        #pragma unroll
        for (int j = 0; j < 4; ++j) {
            int colg = ncol0 + wn + j * 16 + fr;
            float b = bias[colg];
            #pragma unroll
            for (int r = 0; r < 4; ++r) {
                int rowg = m0 + wm + i * 16 + rq * 4 + r;
                if (rowg < M) {
                    float v = acc[i][j][r] + b;
                    float res;
                    if (is_scale) {
                        // fast stable softplus: max(v,0) + log(1 + exp(-|v|))
                        float sp = fmaxf(v, 0.f) + __logf(1.f + __expf(-fabsf(v)));
                        res = fminf(sp + 0.001f, 100.f);
                    } else {
                        res = fminf(fmaxf(v, -100.f), 100.f);
                    }
                    // NT store: 205 MB of C must not evict the A panels from L3
                    __builtin_nontemporal_store(res, &obase[(size_t)rowg * OUT_DIM + colg]);
                }
            }
        }
    }
}

extern "C" void kernel_launch(void* const* d_in, const int* in_sizes, int n_in,
                              void* d_out, int out_size, void* d_ws, size_t ws_size,
                              hipStream_t stream) {
    const float* x       = (const float*)d_in[0];
    const int* ei        = (const int*)d_in[1];   // int inputs delivered as int32
    const float* Wl1     = (const float*)d_in[2];
    const float* bl1     = (const float*)d_in[3];
    const float* Wr1     = (const float*)d_in[4];
    const float* Wl2     = (const float*)d_in[5];
    const float* bl2     = (const float*)d_in[6];
    const float* Wr2     = (const float*)d_in[7];
    float* out = (float*)d_out;

    char* ws = (char*)d_ws;
    size_t off = 0;
    auto alloc = [&](size_t bytes) -> void* {
        void* p = ws + off;
        off = (off + bytes + 255) & ~(size_t)255;
        return p;
    };
    unsigned short* xb    = (unsigned short*)alloc((size_t)N_NODES * IN_DIM * 2);  // 51.2 MB
    unsigned short* aggb  = (unsigned short*)alloc((size_t)N_NODES * IN_DIM * 2);  // 51.2 MB
    unsigned short* Wb    = (unsigned short*)alloc((size_t)NDIM * KDIM * 2);       // 2 MB
    int* counts           = (int*)alloc((size_t)(N_NODES + 1) * 4);
    int* offs             = (int*)alloc((size_t)(N_NODES + 1) * 4);
    int* cursor           = (int*)alloc((size_t)N_NODES * 4);
    int* bucket           = (int*)alloc((size_t)N_EDGES * 4);                      // 3.2 MB
    int* bsums            = (int*)alloc(64 * 4);

    hipMemsetAsync(counts, 0, (size_t)(N_NODES + 1) * 4, stream);

    const int nb = (N_NODES + 1023) / 1024;   // 49

    prep_kernel<<<XCONV_BLOCKS + COUNT_BLOCKS + WCONV_BLOCKS, 256, 0, stream>>>(
        x, xb, ei, counts, Wl1, Wr1, Wl2, Wr2, Wb);
    scan_local_kernel<<<nb, 1024, 0, stream>>>(counts, offs, bsums, N_NODES);
    scan_apply_kernel<<<nb, 1024, 0, stream>>>(offs, cursor, bsums, counts, N_NODES);
    fill_kernel<<<(N_EDGES + 255) / 256, 256, 0, stream>>>(ei, cursor, bucket);
    aggregate_kernel<<<(N_NODES + 3) / 4, 256, 0, stream>>>(xb, offs, bucket, aggb);

    gemm_kernel<<<NWG, 256, 0, stream>>>(aggb, xb, Wb, bl1, bl2, out);
}